// Round 22
// baseline (1056.039 us; speedup 1.0000x reference)
//
#include <hip/hip_runtime.h>
#include <hip/hip_bf16.h>
#include <math.h>

// Workspace (f32):
//  ua 0 / (ua_ 16777216 unused) / ub 33554432 / ub_ 34603008 / GTa 35651584
//  GTb 37748736 / coef 38273024 / coef2 38535168 / t512 38797312 ; end 38798336

__device__ __forceinline__ float gelu_f(float x) {
  float t = tanhf(0.7978845608028654f * (x + 0.044715f * x * x * x));
  return 0.5f * x * (1.0f + t);
}

__device__ __forceinline__ float2 cmulf(float2 a, float2 b) {
  return make_float2(a.x * b.x - a.y * b.y, a.x * b.y + a.y * b.x);
}

__global__ void ktab(float2* __restrict__ t512) {
  int k = blockIdx.x * 256 + threadIdx.x;
  if (k < 512) {
    float a = (float)((double)k * (6.283185307179586 / 512.0));
    t512[k] = make_float2(cosf(a), sinf(a));
  }
}

template <int HW>
__global__ __launch_bounds__(256) void kenc(const float* __restrict__ xin,
                                            const float* __restrict__ uin,
                                            const float* __restrict__ w,
                                            const float* __restrict__ b,
                                            float* __restrict__ out) {
  int p = blockIdx.x * 256 + threadIdx.x;
  float i0 = xin[p], i1 = xin[HW + p];
  float i2 = uin[p], i3 = uin[HW + p];
  for (int c = 0; c < 64; ++c)
    out[(size_t)c * HW + p] =
        w[c * 4 + 0] * i0 + w[c * 4 + 1] * i1 + w[c * 4 + 2] * i2 + w[c * 4 + 3] * i3 + b[c];
}

// fwd DFT stage1 (along w) via Goertzel.
template <int H, int MUL>
__global__ __launch_bounds__(256) void kfwd1(const float* __restrict__ x, float2* __restrict__ G,
                                             const float2* __restrict__ tw, float fs) {
  constexpr int PAD = H + 8;
  __shared__ float sm[8 * PAD];
  int c = blockIdx.x / (H / 8);
  int h8 = blockIdx.x % (H / 8);
  const float* src = x + ((size_t)c * H + h8 * 8) * H;
  for (int i = threadIdx.x; i < 2 * H; i += 256) {
    float4 g = ((const float4*)src)[i];
    int r = (i * 4) >> (H == 512 ? 9 : 7);
    int col = (i * 4) & (H - 1);
    *(float4*)&sm[r * PAD + col] = g;
  }
  __syncthreads();
  int kc = threadIdx.x >> 3;
  int hl = threadIdx.x & 7;
  float2 w0 = tw[(kc * MUL) & 511];
  float twoc = 2.f * w0.x;
  const float* row = sm + hl * PAD;
  float v1 = 0.f, v2 = 0.f;
#pragma unroll 4
  for (int w = 0; w < H; w += 2) {
    v2 = fmaf(twoc, v1, row[w] - v2);
    v1 = fmaf(twoc, v2, row[w + 1] - v1);
  }
  int h = h8 * 8 + hl;
  G[((size_t)c * 32 + kc) * H + h] =
      make_float2(fs * fmaf(w0.x, v1, -v2), fs * (w0.y * v1));
}

// fwd DFT stage2 (along h)
template <int H, int MUL>
__global__ __launch_bounds__(256) void kfwd2(const float2* __restrict__ G, float2* __restrict__ coeff,
                                             const float2* __restrict__ tw, int cbase) {
  __shared__ float2 gs[H];
  int c = blockIdx.x >> 5, kc = blockIdx.x & 31;
  const float2* gr = G + ((size_t)c * 32 + kc) * H;
  for (int i = threadIdx.x; i < H; i += 256) gs[i] = gr[i];
  __syncthreads();
  int jr = threadIdx.x >> 3, sub = threadIdx.x & 7;
  int f = jr - 16;
  float2 cur = tw[(f * sub * MUL) & 511];
  float2 step = tw[(f * 8 * MUL) & 511];
  float re = 0.f, im = 0.f;
  for (int j = 0; j < H / 8; ++j) {
    float2 g = gs[sub + 8 * j];
    re += g.x * cur.x + g.y * cur.y;
    im += g.y * cur.x - g.x * cur.y;
    cur = cmulf(cur, step);
  }
  for (int d = 1; d < 8; d <<= 1) {
    re += __shfl_down(re, d, 8);
    im += __shfl_down(im, d, 8);
  }
  if (sub == 0) coeff[(size_t)(cbase + c) * 1024 + jr * 32 + kc] = make_float2(re, im);
}

__global__ __launch_bounds__(256) void kmix(const float* __restrict__ Are,
                                            const float* __restrict__ Aim,
                                            const float2* __restrict__ cin,
                                            float2* __restrict__ cout) {
  int idx = blockIdx.x * 256 + threadIdx.x;
  int mn = idx & 1023;
  int o = idx >> 10;
  const float* ar = Are + (size_t)o * 131072 + mn;
  const float* ai = Aim + (size_t)o * 131072 + mn;
  float re = 0.f, im = 0.f;
  for (int i = 0; i < 128; ++i) {
    float wr = ar[(size_t)i * 1024];
    float wi = ai[(size_t)i * 1024];
    float2 x = cin[(size_t)i * 1024 + mn];
    re += wr * x.x - wi * x.y;
    im += wr * x.y + wi * x.x;
  }
  cout[(size_t)o * 1024 + mn] = make_float2(re, im);
}

// inverse stage1 (along jr); wgt folded here.
template <int H, int MUL>
__global__ __launch_bounds__(256) void kinv1(const float2* __restrict__ coeff, float2* __restrict__ T,
                                             const float2* __restrict__ tw, int cbase) {
  __shared__ float2 cs[1024];
  int c = blockIdx.x / (H / 8);
  int h8 = blockIdx.x % (H / 8);
  const float2* cr = coeff + (size_t)(cbase + c) * 1024;
  for (int i = threadIdx.x; i < 1024; i += 256) cs[i] = cr[i];
  __syncthreads();
  int kc = threadIdx.x & 31;
  int hl = threadIdx.x >> 5;
  int h = h8 * 8 + hl;
  float2 cur = tw[((-16) * h * MUL) & 511];
  float2 step = tw[(h * MUL) & 511];
  float re = 0.f, im = 0.f;
  for (int jr = 0; jr < 32; ++jr) {
    float2 x = cs[jr * 32 + kc];
    re += x.x * cur.x - x.y * cur.y;
    im += x.x * cur.y + x.y * cur.x;
    cur = cmulf(cur, step);
  }
  float wgt = (kc == 0) ? 1.f : 2.f;
  T[((size_t)c * H + h) * 32 + kc] = make_float2(re * wgt, im * wgt);
}

// FUSED inverse stage2 + residual MLP.
// Block = 64 contiguous pixels of one row h (64 | H), all 64 channels.
// Phase 0: stage T[c][h][*] for all c (16KB) + W1. Phase 1: c2r into Xs.
// Phase 2: GEMM1+gelu -> Xs. Phase 3: GEMM2+gelu residual RMW into uio.
template <int H, int MUL, int HW>
__global__ __launch_bounds__(256) void kinvconv(const float2* __restrict__ T,
                                                float* __restrict__ uio,
                                                const float* __restrict__ w1,
                                                const float* __restrict__ b1,
                                                const float* __restrict__ w2,
                                                const float* __restrict__ b2,
                                                const float2* __restrict__ tw) {
  __shared__ float2 Ts[2048];
  __shared__ float Xs[64][65];
  __shared__ float Ws[64][65];
  int p0 = blockIdx.x * 64;
  int h = p0 / H;
  int w0 = p0 % H;
  int t = threadIdx.x;
  for (int i = t; i < 2048; i += 256) {
    int c = i >> 5, kc = i & 31;
    Ts[i] = T[((size_t)c * H + h) * 32 + kc];
  }
  for (int i = t; i < 4096; i += 256) Ws[i >> 6][i & 63] = w1[i];
  __syncthreads();
  int cb = (t >> 4) * 4;  // 4 channels (doubles as 4 out-channels later)
  int pb = (t & 15) * 4;  // 4 pixels
  float acc[16];
  // ---- phase 1: c2r inverse ----
  {
    float2 s0 = tw[((w0 + pb + 0) * MUL) & 511];
    float2 s1 = tw[((w0 + pb + 1) * MUL) & 511];
    float2 s2 = tw[((w0 + pb + 2) * MUL) & 511];
    float2 s3 = tw[((w0 + pb + 3) * MUL) & 511];
    float2 c0 = make_float2(1.f, 0.f), c1 = c0, c2 = c0, c3 = c0;
#pragma unroll
    for (int i = 0; i < 16; ++i) acc[i] = 0.f;
    const float2* t0 = &Ts[(cb + 0) * 32];
    const float2* t1 = &Ts[(cb + 1) * 32];
    const float2* t2 = &Ts[(cb + 2) * 32];
    const float2* t3 = &Ts[(cb + 3) * 32];
    for (int kc = 0; kc < 32; ++kc) {
      float2 v0 = t0[kc], v1 = t1[kc], v2 = t2[kc], v3 = t3[kc];
      acc[0] += v0.x * c0.x - v0.y * c0.y;
      acc[1] += v0.x * c1.x - v0.y * c1.y;
      acc[2] += v0.x * c2.x - v0.y * c2.y;
      acc[3] += v0.x * c3.x - v0.y * c3.y;
      acc[4] += v1.x * c0.x - v1.y * c0.y;
      acc[5] += v1.x * c1.x - v1.y * c1.y;
      acc[6] += v1.x * c2.x - v1.y * c2.y;
      acc[7] += v1.x * c3.x - v1.y * c3.y;
      acc[8] += v2.x * c0.x - v2.y * c0.y;
      acc[9] += v2.x * c1.x - v2.y * c1.y;
      acc[10] += v2.x * c2.x - v2.y * c2.y;
      acc[11] += v2.x * c3.x - v2.y * c3.y;
      acc[12] += v3.x * c0.x - v3.y * c0.y;
      acc[13] += v3.x * c1.x - v3.y * c1.y;
      acc[14] += v3.x * c2.x - v3.y * c2.y;
      acc[15] += v3.x * c3.x - v3.y * c3.y;
      c0 = cmulf(c0, s0);
      c1 = cmulf(c1, s1);
      c2 = cmulf(c2, s2);
      c3 = cmulf(c3, s3);
    }
#pragma unroll
    for (int i = 0; i < 4; ++i)
#pragma unroll
      for (int j = 0; j < 4; ++j) Xs[cb + i][pb + j] = acc[i * 4 + j];
  }
  __syncthreads();
  // ---- phase 2: GEMM1 ----
#pragma unroll
  for (int i = 0; i < 4; ++i) {
    float bi = b1[cb + i];
#pragma unroll
    for (int j = 0; j < 4; ++j) acc[i * 4 + j] = bi;
  }
  for (int ci = 0; ci < 64; ++ci) {
    float a0 = Ws[cb + 0][ci], a1 = Ws[cb + 1][ci], a2 = Ws[cb + 2][ci], a3 = Ws[cb + 3][ci];
    float x0 = Xs[ci][pb + 0], x1 = Xs[ci][pb + 1], x2 = Xs[ci][pb + 2], x3 = Xs[ci][pb + 3];
    acc[0] = fmaf(a0, x0, acc[0]); acc[1] = fmaf(a0, x1, acc[1]);
    acc[2] = fmaf(a0, x2, acc[2]); acc[3] = fmaf(a0, x3, acc[3]);
    acc[4] = fmaf(a1, x0, acc[4]); acc[5] = fmaf(a1, x1, acc[5]);
    acc[6] = fmaf(a1, x2, acc[6]); acc[7] = fmaf(a1, x3, acc[7]);
    acc[8] = fmaf(a2, x0, acc[8]); acc[9] = fmaf(a2, x1, acc[9]);
    acc[10] = fmaf(a2, x2, acc[10]); acc[11] = fmaf(a2, x3, acc[11]);
    acc[12] = fmaf(a3, x0, acc[12]); acc[13] = fmaf(a3, x1, acc[13]);
    acc[14] = fmaf(a3, x2, acc[14]); acc[15] = fmaf(a3, x3, acc[15]);
  }
  __syncthreads();  // reads of Xs/Ws done
#pragma unroll
  for (int i = 0; i < 4; ++i)
#pragma unroll
    for (int j = 0; j < 4; ++j) Xs[cb + i][pb + j] = gelu_f(acc[i * 4 + j]);
  for (int i = t; i < 4096; i += 256) Ws[i >> 6][i & 63] = w2[i];
  __syncthreads();
  // ---- phase 3: GEMM2 + residual ----
#pragma unroll
  for (int i = 0; i < 4; ++i) {
    float bi = b2[cb + i];
#pragma unroll
    for (int j = 0; j < 4; ++j) acc[i * 4 + j] = bi;
  }
  for (int ci = 0; ci < 64; ++ci) {
    float a0 = Ws[cb + 0][ci], a1 = Ws[cb + 1][ci], a2 = Ws[cb + 2][ci], a3 = Ws[cb + 3][ci];
    float x0 = Xs[ci][pb + 0], x1 = Xs[ci][pb + 1], x2 = Xs[ci][pb + 2], x3 = Xs[ci][pb + 3];
    acc[0] = fmaf(a0, x0, acc[0]); acc[1] = fmaf(a0, x1, acc[1]);
    acc[2] = fmaf(a0, x2, acc[2]); acc[3] = fmaf(a0, x3, acc[3]);
    acc[4] = fmaf(a1, x0, acc[4]); acc[5] = fmaf(a1, x1, acc[5]);
    acc[6] = fmaf(a1, x2, acc[6]); acc[7] = fmaf(a1, x3, acc[7]);
    acc[8] = fmaf(a2, x0, acc[8]); acc[9] = fmaf(a2, x1, acc[9]);
    acc[10] = fmaf(a2, x2, acc[10]); acc[11] = fmaf(a2, x3, acc[11]);
    acc[12] = fmaf(a3, x0, acc[12]); acc[13] = fmaf(a3, x1, acc[13]);
    acc[14] = fmaf(a3, x2, acc[14]); acc[15] = fmaf(a3, x3, acc[15]);
  }
#pragma unroll
  for (int i = 0; i < 4; ++i) {
    float4* dst = (float4*)&uio[(size_t)(cb + i) * HW + p0 + pb];
    float4 u = *dst;
    u.x += gelu_f(acc[i * 4 + 0]);
    u.y += gelu_f(acc[i * 4 + 1]);
    u.z += gelu_f(acc[i * 4 + 2]);
    u.w += gelu_f(acc[i * 4 + 3]);
    *dst = u;
  }
}

__global__ __launch_bounds__(256) void kdecf(const float* __restrict__ ua, const float* __restrict__ w,
                                             const float* __restrict__ b, float* __restrict__ out) {
  int p = blockIdx.x * 256 + threadIdx.x;
  float a0 = b[0], a1 = b[1];
  for (int c = 0; c < 64; ++c) {
    float xv = ua[(size_t)c * 262144 + p];
    a0 = fmaf(w[c], xv, a0);
    a1 = fmaf(w[64 + c], xv, a1);
  }
  out[p] = a0;
  out[262144 + p] = a1;
}

__global__ __launch_bounds__(256) void kcopyf(const float* __restrict__ src, float* __restrict__ out) {
  int p = blockIdx.x * 256 + threadIdx.x;
  out[p] = src[p];
}

extern "C" void kernel_launch(void* const* d_in, const int* in_sizes, int n_in,
                              void* d_out, int out_size, void* d_ws, size_t ws_size,
                              hipStream_t stream) {
  (void)in_sizes; (void)n_in; (void)out_size;
  const float* u_a = (const float*)d_in[0];
  const float* x_a = (const float*)d_in[1];
  const float* u_b = (const float*)d_in[2];
  const float* x_b = (const float*)d_in[3];
  const float* enc_a_w = (const float*)d_in[4];
  const float* enc_a_b = (const float*)d_in[5];
  const float* enc_b_w = (const float*)d_in[6];
  const float* enc_b_b = (const float*)d_in[7];
  const float* dec_w = (const float*)d_in[8];
  const float* dec_b = (const float*)d_in[9];
  const float* c1a_w = (const float*)d_in[10];
  const float* c1a_b = (const float*)d_in[11];
  const float* c2a_w = (const float*)d_in[12];
  const float* c2a_b = (const float*)d_in[13];
  const float* c1b_w = (const float*)d_in[14];
  const float* c1b_b = (const float*)d_in[15];
  const float* c2b_w = (const float*)d_in[16];
  const float* c2b_b = (const float*)d_in[17];
  const float* A_re = (const float*)d_in[18];
  const float* A_im = (const float*)d_in[19];

  if (ws_size < (size_t)38798336 * 4) return;

  float* F = (float*)d_ws;
  float* ua = F;
  float* ub = F + 33554432;
  float2* GTa = (float2*)(F + 35651584);
  float2* GTb = (float2*)(F + 37748736);
  float2* coef = (float2*)(F + 38273024);
  float2* coef2 = (float2*)(F + 38535168);
  float2* t512 = (float2*)(F + 38797312);
  float* out = (float*)d_out;

  ktab<<<2, 256, 0, stream>>>(t512);

  const float FA = 1.f / 262144.f, FB = 1.f / 16384.f;
  kenc<262144><<<1024, 256, 0, stream>>>(x_a, u_a, enc_a_w, enc_a_b, ua);
  kenc<16384><<<64, 256, 0, stream>>>(x_b, u_b, enc_b_w, enc_b_b, ub);
  for (int l = 0; l < 4; ++l) {
    kfwd1<512, 1><<<4096, 256, 0, stream>>>(ua, GTa, t512, FA);
    kfwd2<512, 1><<<2048, 256, 0, stream>>>(GTa, coef, t512, 0);
    kfwd1<128, 4><<<1024, 256, 0, stream>>>(ub, GTb, t512, FB);
    kfwd2<128, 4><<<2048, 256, 0, stream>>>(GTb, coef, t512, 64);
    int nout = (l < 3) ? 128 : 64;  // layer 3: B outputs unused
    kmix<<<nout * 4, 256, 0, stream>>>(A_re + (size_t)l * 16777216,
                                       A_im + (size_t)l * 16777216, coef, coef2);
    kinv1<512, 1><<<4096, 256, 0, stream>>>(coef2, GTa, t512, 0);
    kinvconv<512, 1, 262144><<<4096, 256, 0, stream>>>(GTa, ua, c1a_w + l * 4096,
                                                       c1a_b + l * 64, c2a_w + l * 4096,
                                                       c2a_b + l * 64, t512);
    if (l < 3) {
      kinv1<128, 4><<<1024, 256, 0, stream>>>(coef2, GTb, t512, 64);
      kinvconv<128, 4, 16384><<<256, 256, 0, stream>>>(GTb, ub, c1b_w + l * 4096,
                                                       c1b_b + l * 64, c2b_w + l * 4096,
                                                       c2b_b + l * 64, t512);
    }
  }

  // FLOAT32 outputs, reference order: [dec(ua) (2,512,512); ub (64,128,128)]
  kdecf<<<1024, 256, 0, stream>>>(ua, dec_w, dec_b, out);
  kcopyf<<<4096, 256, 0, stream>>>(ub, out + 524288);
}

// Round 23
// 958.540 us; speedup vs baseline: 1.1017x; 1.1017x over previous
//
#include <hip/hip_runtime.h>
#include <hip/hip_bf16.h>
#include <math.h>

// Workspace (f32):
//  ua 0 / ub 33554432 / GTa 35651584 / GTb 37748736 / coef 38273024
//  coef2 38535168 / t512 38797312 ; end 38798336

__device__ __forceinline__ float gelu_f(float x) {
  float t = tanhf(0.7978845608028654f * (x + 0.044715f * x * x * x));
  return 0.5f * x * (1.0f + t);
}

__device__ __forceinline__ float2 cmulf(float2 a, float2 b) {
  return make_float2(a.x * b.x - a.y * b.y, a.x * b.y + a.y * b.x);
}

__global__ void ktab(float2* __restrict__ t512) {
  int k = blockIdx.x * 256 + threadIdx.x;
  if (k < 512) {
    float a = (float)((double)k * (6.283185307179586 / 512.0));
    t512[k] = make_float2(cosf(a), sinf(a));
  }
}

template <int HW>
__global__ __launch_bounds__(256) void kenc(const float* __restrict__ xin,
                                            const float* __restrict__ uin,
                                            const float* __restrict__ w,
                                            const float* __restrict__ b,
                                            float* __restrict__ out) {
  int p = blockIdx.x * 256 + threadIdx.x;
  float i0 = xin[p], i1 = xin[HW + p];
  float i2 = uin[p], i3 = uin[HW + p];
  for (int c = 0; c < 64; ++c)
    out[(size_t)c * HW + p] =
        w[c * 4 + 0] * i0 + w[c * 4 + 1] * i1 + w[c * 4 + 2] * i2 + w[c * 4 + 3] * i3 + b[c];
}

// fwd DFT stage1 (along w) via Goertzel.
template <int H, int MUL>
__global__ __launch_bounds__(256) void kfwd1(const float* __restrict__ x, float2* __restrict__ G,
                                             const float2* __restrict__ tw, float fs) {
  constexpr int PAD = H + 8;
  __shared__ float sm[8 * PAD];
  int c = blockIdx.x / (H / 8);
  int h8 = blockIdx.x % (H / 8);
  const float* src = x + ((size_t)c * H + h8 * 8) * H;
  for (int i = threadIdx.x; i < 2 * H; i += 256) {
    float4 g = ((const float4*)src)[i];
    int r = (i * 4) >> (H == 512 ? 9 : 7);
    int col = (i * 4) & (H - 1);
    *(float4*)&sm[r * PAD + col] = g;
  }
  __syncthreads();
  int kc = threadIdx.x >> 3;
  int hl = threadIdx.x & 7;
  float2 w0 = tw[(kc * MUL) & 511];
  float twoc = 2.f * w0.x;
  const float* row = sm + hl * PAD;
  float v1 = 0.f, v2 = 0.f;
#pragma unroll 4
  for (int w = 0; w < H; w += 2) {
    v2 = fmaf(twoc, v1, row[w] - v2);
    v1 = fmaf(twoc, v2, row[w + 1] - v1);
  }
  int h = h8 * 8 + hl;
  G[((size_t)c * 32 + kc) * H + h] =
      make_float2(fs * fmaf(w0.x, v1, -v2), fs * (w0.y * v1));
}

// fwd DFT stage2 (along h)
template <int H, int MUL>
__global__ __launch_bounds__(256) void kfwd2(const float2* __restrict__ G, float2* __restrict__ coeff,
                                             const float2* __restrict__ tw, int cbase) {
  __shared__ float2 gs[H];
  int c = blockIdx.x >> 5, kc = blockIdx.x & 31;
  const float2* gr = G + ((size_t)c * 32 + kc) * H;
  for (int i = threadIdx.x; i < H; i += 256) gs[i] = gr[i];
  __syncthreads();
  int jr = threadIdx.x >> 3, sub = threadIdx.x & 7;
  int f = jr - 16;
  float2 cur = tw[(f * sub * MUL) & 511];
  float2 step = tw[(f * 8 * MUL) & 511];
  float re = 0.f, im = 0.f;
  for (int j = 0; j < H / 8; ++j) {
    float2 g = gs[sub + 8 * j];
    re += g.x * cur.x + g.y * cur.y;
    im += g.y * cur.x - g.x * cur.y;
    cur = cmulf(cur, step);
  }
  for (int d = 1; d < 8; d <<= 1) {
    re += __shfl_down(re, d, 8);
    im += __shfl_down(im, d, 8);
  }
  if (sub == 0) coeff[(size_t)(cbase + c) * 1024 + jr * 32 + kc] = make_float2(re, im);
}

__global__ __launch_bounds__(256) void kmix(const float* __restrict__ Are,
                                            const float* __restrict__ Aim,
                                            const float2* __restrict__ cin,
                                            float2* __restrict__ cout) {
  int idx = blockIdx.x * 256 + threadIdx.x;
  int mn = idx & 1023;
  int o = idx >> 10;
  const float* ar = Are + (size_t)o * 131072 + mn;
  const float* ai = Aim + (size_t)o * 131072 + mn;
  float re = 0.f, im = 0.f;
  for (int i = 0; i < 128; ++i) {
    float wr = ar[(size_t)i * 1024];
    float wi = ai[(size_t)i * 1024];
    float2 x = cin[(size_t)i * 1024 + mn];
    re += wr * x.x - wi * x.y;
    im += wr * x.y + wi * x.x;
  }
  cout[(size_t)o * 1024 + mn] = make_float2(re, im);
}

// inverse stage1 (along jr); wgt folded here.
template <int H, int MUL>
__global__ __launch_bounds__(256) void kinv1(const float2* __restrict__ coeff, float2* __restrict__ T,
                                             const float2* __restrict__ tw, int cbase) {
  __shared__ float2 cs[1024];
  int c = blockIdx.x / (H / 8);
  int h8 = blockIdx.x % (H / 8);
  const float2* cr = coeff + (size_t)(cbase + c) * 1024;
  for (int i = threadIdx.x; i < 1024; i += 256) cs[i] = cr[i];
  __syncthreads();
  int kc = threadIdx.x & 31;
  int hl = threadIdx.x >> 5;
  int h = h8 * 8 + hl;
  float2 cur = tw[((-16) * h * MUL) & 511];
  float2 step = tw[(h * MUL) & 511];
  float re = 0.f, im = 0.f;
  for (int jr = 0; jr < 32; ++jr) {
    float2 x = cs[jr * 32 + kc];
    re += x.x * cur.x - x.y * cur.y;
    im += x.x * cur.y + x.y * cur.x;
    cur = cmulf(cur, step);
  }
  float wgt = (kc == 0) ? 1.f : 2.f;
  T[((size_t)c * H + h) * 32 + kc] = make_float2(re * wgt, im * wgt);
}

// FUSED inverse stage2 + residual MLP, LDS-optimized:
// Ts padded (stride 33), Xs/Ws stride 68 (aligned float4, rotating banks),
// W transposed in LDS (one b128 per GEMM iter), Ts/Ws share one buffer.
template <int H, int MUL, int HW>
__global__ __launch_bounds__(256) void kinvconv(const float2* __restrict__ T,
                                                float* __restrict__ uio,
                                                const float* __restrict__ w1,
                                                const float* __restrict__ b1,
                                                const float* __restrict__ w2,
                                                const float* __restrict__ b2,
                                                const float2* __restrict__ tw) {
  __shared__ __align__(16) float Xs[64 * 68];
  __shared__ __align__(16) float UB[64 * 68];  // Ts (float2, stride 33) then Ws[ci][oc] (stride 68)
  float2* Ts = (float2*)UB;
  int p0 = blockIdx.x * 64;
  int h = p0 / H;
  int w0 = p0 % H;
  int t = threadIdx.x;
  for (int i = t; i < 2048; i += 256) {
    int c = i >> 5, kc = i & 31;
    Ts[c * 33 + kc] = T[((size_t)c * H + h) * 32 + kc];
  }
  __syncthreads();
  int cb = (t >> 4) * 4;  // 4 channels / out-channels
  int pb = (t & 15) * 4;  // 4 pixels
  float acc[16];
  // ---- phase 1: c2r inverse (rotators per pixel) ----
  {
    float2 s0 = tw[((w0 + pb + 0) * MUL) & 511];
    float2 s1 = tw[((w0 + pb + 1) * MUL) & 511];
    float2 s2 = tw[((w0 + pb + 2) * MUL) & 511];
    float2 s3 = tw[((w0 + pb + 3) * MUL) & 511];
    float2 c0 = make_float2(1.f, 0.f), c1 = c0, c2 = c0, c3 = c0;
#pragma unroll
    for (int i = 0; i < 16; ++i) acc[i] = 0.f;
    const float2* t0 = &Ts[(cb + 0) * 33];
    const float2* t1 = &Ts[(cb + 1) * 33];
    const float2* t2 = &Ts[(cb + 2) * 33];
    const float2* t3 = &Ts[(cb + 3) * 33];
    for (int kc = 0; kc < 32; ++kc) {
      float2 v0 = t0[kc], v1 = t1[kc], v2 = t2[kc], v3 = t3[kc];
      acc[0] += v0.x * c0.x - v0.y * c0.y;
      acc[1] += v0.x * c1.x - v0.y * c1.y;
      acc[2] += v0.x * c2.x - v0.y * c2.y;
      acc[3] += v0.x * c3.x - v0.y * c3.y;
      acc[4] += v1.x * c0.x - v1.y * c0.y;
      acc[5] += v1.x * c1.x - v1.y * c1.y;
      acc[6] += v1.x * c2.x - v1.y * c2.y;
      acc[7] += v1.x * c3.x - v1.y * c3.y;
      acc[8] += v2.x * c0.x - v2.y * c0.y;
      acc[9] += v2.x * c1.x - v2.y * c1.y;
      acc[10] += v2.x * c2.x - v2.y * c2.y;
      acc[11] += v2.x * c3.x - v2.y * c3.y;
      acc[12] += v3.x * c0.x - v3.y * c0.y;
      acc[13] += v3.x * c1.x - v3.y * c1.y;
      acc[14] += v3.x * c2.x - v3.y * c2.y;
      acc[15] += v3.x * c3.x - v3.y * c3.y;
      c0 = cmulf(c0, s0);
      c1 = cmulf(c1, s1);
      c2 = cmulf(c2, s2);
      c3 = cmulf(c3, s3);
    }
  }
  __syncthreads();  // Ts fully consumed (allow Ws overwrite)
#pragma unroll
  for (int i = 0; i < 4; ++i)
    *(float4*)&Xs[(cb + i) * 68 + pb] =
        make_float4(acc[i * 4 + 0], acc[i * 4 + 1], acc[i * 4 + 2], acc[i * 4 + 3]);
  for (int i = t; i < 4096; i += 256) UB[(i & 63) * 68 + (i >> 6)] = w1[i];  // Ws[ci][oc]
  __syncthreads();
  // ---- phase 2: GEMM1 ----
#pragma unroll
  for (int i = 0; i < 4; ++i) {
    float bi = b1[cb + i];
#pragma unroll
    for (int j = 0; j < 4; ++j) acc[i * 4 + j] = bi;
  }
  for (int ci = 0; ci < 64; ++ci) {
    float4 wv = *(const float4*)&UB[ci * 68 + cb];
    float4 xv = *(const float4*)&Xs[ci * 68 + pb];
    acc[0] = fmaf(wv.x, xv.x, acc[0]); acc[1] = fmaf(wv.x, xv.y, acc[1]);
    acc[2] = fmaf(wv.x, xv.z, acc[2]); acc[3] = fmaf(wv.x, xv.w, acc[3]);
    acc[4] = fmaf(wv.y, xv.x, acc[4]); acc[5] = fmaf(wv.y, xv.y, acc[5]);
    acc[6] = fmaf(wv.y, xv.z, acc[6]); acc[7] = fmaf(wv.y, xv.w, acc[7]);
    acc[8] = fmaf(wv.z, xv.x, acc[8]); acc[9] = fmaf(wv.z, xv.y, acc[9]);
    acc[10] = fmaf(wv.z, xv.z, acc[10]); acc[11] = fmaf(wv.z, xv.w, acc[11]);
    acc[12] = fmaf(wv.w, xv.x, acc[12]); acc[13] = fmaf(wv.w, xv.y, acc[13]);
    acc[14] = fmaf(wv.w, xv.z, acc[14]); acc[15] = fmaf(wv.w, xv.w, acc[15]);
  }
  __syncthreads();  // Xs/Ws reads done
#pragma unroll
  for (int i = 0; i < 4; ++i)
    *(float4*)&Xs[(cb + i) * 68 + pb] =
        make_float4(gelu_f(acc[i * 4 + 0]), gelu_f(acc[i * 4 + 1]),
                    gelu_f(acc[i * 4 + 2]), gelu_f(acc[i * 4 + 3]));
  for (int i = t; i < 4096; i += 256) UB[(i & 63) * 68 + (i >> 6)] = w2[i];
  __syncthreads();
  // ---- phase 3: GEMM2 + residual ----
#pragma unroll
  for (int i = 0; i < 4; ++i) {
    float bi = b2[cb + i];
#pragma unroll
    for (int j = 0; j < 4; ++j) acc[i * 4 + j] = bi;
  }
  for (int ci = 0; ci < 64; ++ci) {
    float4 wv = *(const float4*)&UB[ci * 68 + cb];
    float4 xv = *(const float4*)&Xs[ci * 68 + pb];
    acc[0] = fmaf(wv.x, xv.x, acc[0]); acc[1] = fmaf(wv.x, xv.y, acc[1]);
    acc[2] = fmaf(wv.x, xv.z, acc[2]); acc[3] = fmaf(wv.x, xv.w, acc[3]);
    acc[4] = fmaf(wv.y, xv.x, acc[4]); acc[5] = fmaf(wv.y, xv.y, acc[5]);
    acc[6] = fmaf(wv.y, xv.z, acc[6]); acc[7] = fmaf(wv.y, xv.w, acc[7]);
    acc[8] = fmaf(wv.z, xv.x, acc[8]); acc[9] = fmaf(wv.z, xv.y, acc[9]);
    acc[10] = fmaf(wv.z, xv.z, acc[10]); acc[11] = fmaf(wv.z, xv.w, acc[11]);
    acc[12] = fmaf(wv.w, xv.x, acc[12]); acc[13] = fmaf(wv.w, xv.y, acc[13]);
    acc[14] = fmaf(wv.w, xv.z, acc[14]); acc[15] = fmaf(wv.w, xv.w, acc[15]);
  }
#pragma unroll
  for (int i = 0; i < 4; ++i) {
    float4* dst = (float4*)&uio[(size_t)(cb + i) * HW + p0 + pb];
    float4 u = *dst;
    u.x += gelu_f(acc[i * 4 + 0]);
    u.y += gelu_f(acc[i * 4 + 1]);
    u.z += gelu_f(acc[i * 4 + 2]);
    u.w += gelu_f(acc[i * 4 + 3]);
    *dst = u;
  }
}

__global__ __launch_bounds__(256) void kdecf(const float* __restrict__ ua, const float* __restrict__ w,
                                             const float* __restrict__ b, float* __restrict__ out) {
  int p = blockIdx.x * 256 + threadIdx.x;
  float a0 = b[0], a1 = b[1];
  for (int c = 0; c < 64; ++c) {
    float xv = ua[(size_t)c * 262144 + p];
    a0 = fmaf(w[c], xv, a0);
    a1 = fmaf(w[64 + c], xv, a1);
  }
  out[p] = a0;
  out[262144 + p] = a1;
}

__global__ __launch_bounds__(256) void kcopyf(const float* __restrict__ src, float* __restrict__ out) {
  int p = blockIdx.x * 256 + threadIdx.x;
  out[p] = src[p];
}

extern "C" void kernel_launch(void* const* d_in, const int* in_sizes, int n_in,
                              void* d_out, int out_size, void* d_ws, size_t ws_size,
                              hipStream_t stream) {
  (void)in_sizes; (void)n_in; (void)out_size;
  const float* u_a = (const float*)d_in[0];
  const float* x_a = (const float*)d_in[1];
  const float* u_b = (const float*)d_in[2];
  const float* x_b = (const float*)d_in[3];
  const float* enc_a_w = (const float*)d_in[4];
  const float* enc_a_b = (const float*)d_in[5];
  const float* enc_b_w = (const float*)d_in[6];
  const float* enc_b_b = (const float*)d_in[7];
  const float* dec_w = (const float*)d_in[8];
  const float* dec_b = (const float*)d_in[9];
  const float* c1a_w = (const float*)d_in[10];
  const float* c1a_b = (const float*)d_in[11];
  const float* c2a_w = (const float*)d_in[12];
  const float* c2a_b = (const float*)d_in[13];
  const float* c1b_w = (const float*)d_in[14];
  const float* c1b_b = (const float*)d_in[15];
  const float* c2b_w = (const float*)d_in[16];
  const float* c2b_b = (const float*)d_in[17];
  const float* A_re = (const float*)d_in[18];
  const float* A_im = (const float*)d_in[19];

  if (ws_size < (size_t)38798336 * 4) return;

  float* F = (float*)d_ws;
  float* ua = F;
  float* ub = F + 33554432;
  float2* GTa = (float2*)(F + 35651584);
  float2* GTb = (float2*)(F + 37748736);
  float2* coef = (float2*)(F + 38273024);
  float2* coef2 = (float2*)(F + 38535168);
  float2* t512 = (float2*)(F + 38797312);
  float* out = (float*)d_out;

  ktab<<<2, 256, 0, stream>>>(t512);

  const float FA = 1.f / 262144.f, FB = 1.f / 16384.f;
  kenc<262144><<<1024, 256, 0, stream>>>(x_a, u_a, enc_a_w, enc_a_b, ua);
  kenc<16384><<<64, 256, 0, stream>>>(x_b, u_b, enc_b_w, enc_b_b, ub);
  for (int l = 0; l < 4; ++l) {
    kfwd1<512, 1><<<4096, 256, 0, stream>>>(ua, GTa, t512, FA);
    kfwd2<512, 1><<<2048, 256, 0, stream>>>(GTa, coef, t512, 0);
    kfwd1<128, 4><<<1024, 256, 0, stream>>>(ub, GTb, t512, FB);
    kfwd2<128, 4><<<2048, 256, 0, stream>>>(GTb, coef, t512, 64);
    int nout = (l < 3) ? 128 : 64;  // layer 3: B outputs unused
    kmix<<<nout * 4, 256, 0, stream>>>(A_re + (size_t)l * 16777216,
                                       A_im + (size_t)l * 16777216, coef, coef2);
    kinv1<512, 1><<<4096, 256, 0, stream>>>(coef2, GTa, t512, 0);
    kinvconv<512, 1, 262144><<<4096, 256, 0, stream>>>(GTa, ua, c1a_w + l * 4096,
                                                       c1a_b + l * 64, c2a_w + l * 4096,
                                                       c2a_b + l * 64, t512);
    if (l < 3) {
      kinv1<128, 4><<<1024, 256, 0, stream>>>(coef2, GTb, t512, 64);
      kinvconv<128, 4, 16384><<<256, 256, 0, stream>>>(GTb, ub, c1b_w + l * 4096,
                                                       c1b_b + l * 64, c2b_w + l * 4096,
                                                       c2b_b + l * 64, t512);
    }
  }

  // FLOAT32 outputs, reference order: [dec(ua) (2,512,512); ub (64,128,128)]
  kdecf<<<1024, 256, 0, stream>>>(ua, dec_w, dec_b, out);
  kcopyf<<<4096, 256, 0, stream>>>(ub, out + 524288);
}